// Round 5
// baseline (96791.663 us; speedup 1.0000x reference)
//
#include <hip/hip_runtime.h>
#include <hip/hip_bf16.h>
#include <stdint.h>

#define T_LEN 16384
#define HDIM 512
#define G4 2048
#define CLAMP_MAXV 49688.0f

typedef float f32x4 __attribute__((ext_vector_type(4)));
typedef unsigned int u32x4 __attribute__((ext_vector_type(4)));

// workspace layout (bytes). hfast/bsum overlay inter's head (dead before the
// inter GEMM runs).
#define XG_OFF    0ull
#define HS_OFF    134217728ull   // 16384*2048*4
#define INTER_OFF 167772160ull
#define HFAST_OFF 167772160ull   // 8 KB (2 parities x 512 x 8B atoms)
#define BSUM_OFF  167780352ull   // 8 KB
#define WS_NEED   176177152ull   // INTER_OFF + 16384*128*4

// ---------------------------------------------------------------------------
__global__ __launch_bounds__(256) void init_k(uint64_t* __restrict__ hfast,
                                              const float* __restrict__ b_ih,
                                              const float* __restrict__ b_hh,
                                              float* __restrict__ bsum) {
    int i = blockIdx.x * 256 + threadIdx.x;   // grid 8x256 -> i in [0,2048)
    if (i < 1024) hfast[i] = 0ull;            // tag 0 = h_{-1} ready, h = 0
    bsum[i] = b_ih[i] + b_hh[i];
}

// ---------------------------------------------------------------------------
// C[M,N] = A[M,K] @ B[N,K]^T + bias[N]
// ---------------------------------------------------------------------------
__global__ __launch_bounds__(256) void gemm_abt(const float* __restrict__ A,
                                                const float* __restrict__ B,
                                                const float* __restrict__ bias,
                                                float* __restrict__ C,
                                                int N, int K) {
    __shared__ float As[16][68];
    __shared__ float Bs[16][68];
    const int tid = threadIdx.x;
    const int bm = blockIdx.x << 6, bn = blockIdx.y << 6;
    const int tx = tid & 15, ty = tid >> 4;
    const int lr = tid >> 2, lk = (tid & 3) << 2;
    float acc[4][4] = {};
    const float* Ap = A + (size_t)(bm + lr) * K + lk;
    const float* Bp = B + (size_t)(bn + lr) * K + lk;
    for (int kt = 0; kt < K; kt += 16) {
        float4 av = *(const float4*)(Ap + kt);
        float4 bv = *(const float4*)(Bp + kt);
        __syncthreads();
        As[lk + 0][lr] = av.x; As[lk + 1][lr] = av.y;
        As[lk + 2][lr] = av.z; As[lk + 3][lr] = av.w;
        Bs[lk + 0][lr] = bv.x; Bs[lk + 1][lr] = bv.y;
        Bs[lk + 2][lr] = bv.z; Bs[lk + 3][lr] = bv.w;
        __syncthreads();
#pragma unroll
        for (int kk = 0; kk < 16; ++kk) {
            float4 a4 = *(const float4*)&As[kk][ty << 2];
            float4 b4 = *(const float4*)&Bs[kk][tx << 2];
            acc[0][0] += a4.x * b4.x; acc[0][1] += a4.x * b4.y;
            acc[0][2] += a4.x * b4.z; acc[0][3] += a4.x * b4.w;
            acc[1][0] += a4.y * b4.x; acc[1][1] += a4.y * b4.y;
            acc[1][2] += a4.y * b4.z; acc[1][3] += a4.y * b4.w;
            acc[2][0] += a4.z * b4.x; acc[2][1] += a4.z * b4.y;
            acc[2][2] += a4.z * b4.z; acc[2][3] += a4.z * b4.w;
            acc[3][0] += a4.w * b4.x; acc[3][1] += a4.w * b4.y;
            acc[3][2] += a4.w * b4.z; acc[3][3] += a4.w * b4.w;
        }
    }
    const int col = bn + (tx << 2);
    float4 bv4 = *(const float4*)&bias[col];
#pragma unroll
    for (int i = 0; i < 4; ++i) {
        int row = bm + (ty << 2) + i;
        float4 o;
        o.x = acc[i][0] + bv4.x; o.y = acc[i][1] + bv4.y;
        o.z = acc[i][2] + bv4.z; o.w = acc[i][3] + bv4.w;
        *(float4*)&C[(size_t)row * N + col] = o;
    }
}

// ---------------------------------------------------------------------------
// Persistent LSTM scan — wave-autonomous dataflow, zero barriers, LLC-coherent
// (agent-level sc0 sc1) h broadcast. 32 blocks x 512 threads = 256 waves; wave
// (j,wv) owns h-elements e0=16j+2wv, e0+1 (8 gate rows, full K=512).
// Per step, per lane: poll 8 adjacent atoms (4x dwordx4, one LLC round),
// 8 FMAs on polled regs, 6-stage butterfly (8 rows), activations redundant in
// all lanes, lane 0 publishes both atoms with one 16B sc0 sc1 store.
// Parity double-buffer is sufficient: publishing tag t+2 into buffer t&1
// implies all waves already consumed every tag-t atom.
// W_hh rows pinned in VGPRs via asm loads; xg via wave-uniform s_load
// (lgkm domain -> never drained by the poll's vmcnt(0)).
// ---------------------------------------------------------------------------
__global__ __launch_bounds__(512, 1) void lstm_scan(const float* __restrict__ W_hh,
                                                    const float* __restrict__ xg,
                                                    float* __restrict__ hs,
                                                    uint64_t* __restrict__ hfast) {
    const int tid = threadIdx.x;
    const int wv = tid >> 6;
    const int lane = tid & 63;
    const int j = blockIdx.x;            // 0..31
    const int e0 = (j << 4) + (wv << 1); // wave's first h-element

    // ---- W_hh: 8 rows x 8 k-elements per lane, pinned via asm loads ----
    // row r: gate = r>>1, elem-offset = r&1 -> global row (gate<<9)+e0+(r&1)
    f32x4 w[16];
#pragma unroll
    for (int r = 0; r < 8; ++r) {
        const float* wr = W_hh + (size_t)(((r >> 1) << 9) + e0 + (r & 1)) * HDIM
                        + (lane << 3);
        asm volatile("global_load_dwordx4 %0, %2, off\n\t"
                     "global_load_dwordx4 %1, %2, off offset:16\n\t"
                     "s_waitcnt vmcnt(0)"
                     : "=v"(w[2 * r]), "=v"(w[2 * r + 1]) : "v"(wr));
    }

    // xg scalar-prefetch pipeline (wave-uniform -> s_load, lgkm domain)
    const int wvu = __builtin_amdgcn_readfirstlane(wv);
    const float* xbase = xg + (j << 4) + (wvu << 1);
    float2 xc[4], xn[4];
#pragma unroll
    for (int g = 0; g < 4; ++g) xc[g] = *(const float2*)(xbase + (g << 9));

    const unsigned int* pb0 = (const unsigned int*)hfast + (lane << 4);
    const unsigned int* pb1 = (const unsigned int*)(hfast + 512) + (lane << 4);

    float c0 = 0.f, c1 = 0.f;            // cell state (redundant in all lanes)
    for (int t = 0; t < T_LEN; ++t) {
        // ---- poll my 8 atoms (elements [8*lane, 8*lane+8)) for tag t ----
        const unsigned int* pb = (t & 1) ? pb1 : pb0;
        u32x4 q0, q1, q2, q3;
        const unsigned int tt = (unsigned int)t;
        int rounds = 0;
        for (;;) {
            asm volatile(
                "global_load_dwordx4 %0, %4, off sc0 sc1\n\t"
                "global_load_dwordx4 %1, %4, off offset:16 sc0 sc1\n\t"
                "global_load_dwordx4 %2, %4, off offset:32 sc0 sc1\n\t"
                "global_load_dwordx4 %3, %4, off offset:48 sc0 sc1\n\t"
                "s_waitcnt vmcnt(0)"
                : "=v"(q0), "=v"(q1), "=v"(q2), "=v"(q3)
                : "v"(pb) : "memory");
            if ((q0.y == tt) & (q0.w == tt) & (q1.y == tt) & (q1.w == tt) &
                (q2.y == tt) & (q2.w == tt) & (q3.y == tt) & (q3.w == tt)) break;
            if (++rounds > (1 << 20)) break;   // hang-breaker (never in practice)
        }

        // issue next step's xg scalar loads (consumed after next butterfly)
        if (t + 1 < T_LEN) {
            const float* xp = xbase + (size_t)(t + 1) * G4;
#pragma unroll
            for (int g = 0; g < 4; ++g) xn[g] = *(const float2*)(xp + (g << 9));
        }

        // ---- 8 FMAs on the polled h values (k = 8*lane .. 8*lane+7) ----
        const float h0 = __uint_as_float(q0.x), h1 = __uint_as_float(q0.z);
        const float h2 = __uint_as_float(q1.x), h3 = __uint_as_float(q1.z);
        const float h4 = __uint_as_float(q2.x), h5 = __uint_as_float(q2.z);
        const float h6 = __uint_as_float(q3.x), h7 = __uint_as_float(q3.z);
        float p[8];
#pragma unroll
        for (int r = 0; r < 8; ++r) {
            p[r] = w[2 * r][0] * h0 + w[2 * r][1] * h1
                 + w[2 * r][2] * h2 + w[2 * r][3] * h3
                 + w[2 * r + 1][0] * h4 + w[2 * r + 1][1] * h5
                 + w[2 * r + 1][2] * h6 + w[2 * r + 1][3] * h7;
        }

        // ---- butterfly reduce over 64 lanes (all lanes end with full sums) --
#pragma unroll
        for (int s = 1; s < 64; s <<= 1) {
#pragma unroll
            for (int r = 0; r < 8; ++r) p[r] += __shfl_xor(p[r], s);
        }

        // add x-gate contribution (uniform scalars)
#pragma unroll
        for (int r = 0; r < 8; ++r)
            p[r] += (r & 1) ? xc[r >> 1].y : xc[r >> 1].x;

        // ---- gates -> c,h for the wave's 2 elements (redundant per lane) ----
        // p[2g+eo]: g0=i, g1=f, g2=g(tanh), g3=o
        float hv0, hv1;
        {
            float i0 = 1.f / (1.f + __expf(-p[0]));
            float f0 = 1.f / (1.f + __expf(-p[2]));
            float g0 = 2.f / (1.f + __expf(-2.f * p[4])) - 1.f;
            float o0 = 1.f / (1.f + __expf(-p[6]));
            c0 = f0 * c0 + i0 * g0;
            hv0 = o0 * (2.f / (1.f + __expf(-2.f * c0)) - 1.f);
            float i1 = 1.f / (1.f + __expf(-p[1]));
            float f1 = 1.f / (1.f + __expf(-p[3]));
            float g1 = 2.f / (1.f + __expf(-2.f * p[5])) - 1.f;
            float o1 = 1.f / (1.f + __expf(-p[7]));
            c1 = f1 * c1 + i1 * g1;
            hv1 = o1 * (2.f / (1.f + __expf(-2.f * c1)) - 1.f);
        }

        // ---- publish (lane 0): hs row slice + both atoms in one 16B store --
        if (lane == 0) {
            float2 hw; hw.x = hv0; hw.y = hv1;
            *(float2*)&hs[(size_t)t * HDIM + e0] = hw;
            u32x4 pk;
            pk.x = __float_as_uint(hv0); pk.y = (unsigned int)(t + 1);
            pk.z = __float_as_uint(hv1); pk.w = (unsigned int)(t + 1);
            const uint64_t* dst = hfast + (((t + 1) & 1) << 9) + e0;
            asm volatile("global_store_dwordx4 %0, %1, off sc0 sc1"
                         :: "v"(dst), "v"(pk) : "memory");
        }

#pragma unroll
        for (int g = 0; g < 4; ++g) xc[g] = xn[g];
    }
}

// ---------------------------------------------------------------------------
__global__ __launch_bounds__(256) void heads_k(const float* __restrict__ inter,
                                               const float* __restrict__ fc1w,
                                               const float* __restrict__ fc1b,
                                               const float* __restrict__ fc2w,
                                               const float* __restrict__ fc2b,
                                               float* __restrict__ out) {
    __shared__ float it[64][128];
    __shared__ float wt[128][56];
    __shared__ float bl[56];
    const int tid = threadIdx.x;
    const int t0 = blockIdx.x << 6;
    for (int q = tid; q < 64 * 32; q += 256) {
        int r = q >> 5, c4 = q & 31;
        *(float4*)&it[r][c4 << 2] =
            *(const float4*)&inter[(size_t)(t0 + r) * 128 + (c4 << 2)];
    }
    for (int q = tid; q < 53 * 32; q += 256) {
        int r = q >> 5, c4 = q & 31;
        float4 v = (r < 16) ? ((const float4*)&fc1w[r * 128])[c4]
                            : ((const float4*)&fc2w[(r - 16) * 128])[c4];
        int k = c4 << 2;
        wt[k + 0][r] = v.x; wt[k + 1][r] = v.y; wt[k + 2][r] = v.z; wt[k + 3][r] = v.w;
    }
    if (tid < 53) bl[tid] = (tid < 16) ? fc1b[tid] : fc2b[tid - 16];
    __syncthreads();
    const int c = tid & 63, rg = tid >> 6;
    if (c < 53) {
        float b = bl[c];
        for (int rr = 0; rr < 16; ++rr) {
            int r = (rg << 4) + rr;
            float acc = b;
#pragma unroll 8
            for (int k = 0; k < 128; k += 4) {
                float4 iv = *(const float4*)&it[r][k];
                acc += iv.x * wt[k][c] + iv.y * wt[k + 1][c] +
                       iv.z * wt[k + 2][c] + iv.w * wt[k + 3][c];
            }
            acc = fminf(fmaxf(acc, 0.f), CLAMP_MAXV);
            int t = t0 + r;
            if (c < 16) out[(size_t)t * 16 + c] = acc;
            else        out[262144 + (size_t)t * 37 + (c - 16)] = acc;
        }
    }
}

// ---------------------------------------------------------------------------
extern "C" void kernel_launch(void* const* d_in, const int* in_sizes, int n_in,
                              void* d_out, int out_size, void* d_ws, size_t ws_size,
                              hipStream_t stream) {
    const float* x     = (const float*)d_in[0];
    const float* W_ih  = (const float*)d_in[1];
    const float* W_hh  = (const float*)d_in[2];
    const float* b_ih  = (const float*)d_in[3];
    const float* b_hh  = (const float*)d_in[4];
    const float* fc_w  = (const float*)d_in[5];
    const float* fc_b  = (const float*)d_in[6];
    const float* fc1_w = (const float*)d_in[7];
    const float* fc1_b = (const float*)d_in[8];
    const float* fc2_w = (const float*)d_in[9];
    const float* fc2_b = (const float*)d_in[10];

    if (ws_size < WS_NEED) return;

    char* ws = (char*)d_ws;
    float*    xg    = (float*)(ws + XG_OFF);
    float*    hs    = (float*)(ws + HS_OFF);
    float*    inter = (float*)(ws + INTER_OFF);
    uint64_t* hfast = (uint64_t*)(ws + HFAST_OFF);
    float*    bsum  = (float*)(ws + BSUM_OFF);
    float*    out   = (float*)d_out;

    hipLaunchKernelGGL(init_k, dim3(8), dim3(256), 0, stream,
                       hfast, b_ih, b_hh, bsum);
    hipLaunchKernelGGL(gemm_abt, dim3(256, 32), dim3(256), 0, stream,
                       x, W_ih, bsum, xg, 2048, 512);
    hipLaunchKernelGGL(lstm_scan, dim3(32), dim3(512), 0, stream,
                       W_hh, xg, hs, hfast);
    hipLaunchKernelGGL(gemm_abt, dim3(256, 2), dim3(256), 0, stream,
                       hs, fc_w, fc_b, inter, 128, 512);
    hipLaunchKernelGGL(heads_k, dim3(256), dim3(256), 0, stream,
                       inter, fc1_w, fc1_b, fc2_w, fc2_b, out);
}

// Round 6
// 29796.329 us; speedup vs baseline: 3.2484x; 3.2484x over previous
//
#include <hip/hip_runtime.h>
#include <hip/hip_bf16.h>
#include <stdint.h>

#define T_LEN 16384
#define HDIM 512
#define G4 2048
#define CLAMP_MAXV 49688.0f

typedef float f32x4 __attribute__((ext_vector_type(4)));

// workspace layout (bytes). atoms/bsum overlay inter's head (dead before the
// inter GEMM runs).
#define XG_OFF    0ull
#define HS_OFF    134217728ull   // 16384*2048*4
#define INTER_OFF 167772160ull
#define ATOM_OFF  167772160ull   // 8 KB (2 parities x 512 x 8B)
#define BSUM_OFF  167780352ull   // 8 KB
#define WS_NEED   176177152ull   // INTER_OFF + 16384*128*4

// ---------------------------------------------------------------------------
__global__ __launch_bounds__(256) void init_k(uint64_t* __restrict__ atoms,
                                              const float* __restrict__ b_ih,
                                              const float* __restrict__ b_hh,
                                              float* __restrict__ bsum) {
    int i = blockIdx.x * 256 + threadIdx.x;   // grid 8x256 -> i in [0,2048)
    if (i < 1024) atoms[i] = 0ull;            // tag 0 = h_{-1} ready, h = 0
    bsum[i] = b_ih[i] + b_hh[i];
}

// ---------------------------------------------------------------------------
// C[M,N] = A[M,K] @ B[N,K]^T + bias[N]
// ---------------------------------------------------------------------------
__global__ __launch_bounds__(256) void gemm_abt(const float* __restrict__ A,
                                                const float* __restrict__ B,
                                                const float* __restrict__ bias,
                                                float* __restrict__ C,
                                                int N, int K) {
    __shared__ float As[16][68];
    __shared__ float Bs[16][68];
    const int tid = threadIdx.x;
    const int bm = blockIdx.x << 6, bn = blockIdx.y << 6;
    const int tx = tid & 15, ty = tid >> 4;
    const int lr = tid >> 2, lk = (tid & 3) << 2;
    float acc[4][4] = {};
    const float* Ap = A + (size_t)(bm + lr) * K + lk;
    const float* Bp = B + (size_t)(bn + lr) * K + lk;
    for (int kt = 0; kt < K; kt += 16) {
        float4 av = *(const float4*)(Ap + kt);
        float4 bv = *(const float4*)(Bp + kt);
        __syncthreads();
        As[lk + 0][lr] = av.x; As[lk + 1][lr] = av.y;
        As[lk + 2][lr] = av.z; As[lk + 3][lr] = av.w;
        Bs[lk + 0][lr] = bv.x; Bs[lk + 1][lr] = bv.y;
        Bs[lk + 2][lr] = bv.z; Bs[lk + 3][lr] = bv.w;
        __syncthreads();
#pragma unroll
        for (int kk = 0; kk < 16; ++kk) {
            float4 a4 = *(const float4*)&As[kk][ty << 2];
            float4 b4 = *(const float4*)&Bs[kk][tx << 2];
            acc[0][0] += a4.x * b4.x; acc[0][1] += a4.x * b4.y;
            acc[0][2] += a4.x * b4.z; acc[0][3] += a4.x * b4.w;
            acc[1][0] += a4.y * b4.x; acc[1][1] += a4.y * b4.y;
            acc[1][2] += a4.y * b4.z; acc[1][3] += a4.y * b4.w;
            acc[2][0] += a4.z * b4.x; acc[2][1] += a4.z * b4.y;
            acc[2][2] += a4.z * b4.z; acc[2][3] += a4.z * b4.w;
            acc[3][0] += a4.w * b4.x; acc[3][1] += a4.w * b4.y;
            acc[3][2] += a4.w * b4.z; acc[3][3] += a4.w * b4.w;
        }
    }
    const int col = bn + (tx << 2);
    float4 bv4 = *(const float4*)&bias[col];
#pragma unroll
    for (int i = 0; i < 4; ++i) {
        int row = bm + (ty << 2) + i;
        float4 o;
        o.x = acc[i][0] + bv4.x; o.y = acc[i][1] + bv4.y;
        o.z = acc[i][2] + bv4.z; o.w = acc[i][3] + bv4.w;
        *(float4*)&C[(size_t)row * N + col] = o;
    }
}

// ---------------------------------------------------------------------------
// Persistent LSTM scan. 32 blocks x 512 threads. Block j owns h elements
// [16j, 16j+16). Local row index r = 4u+g (u=elem 0..15, g=gate i/f/gg/o)
// -> global gate row 512g + 16j + u.
//
// Thread (wv, lam): m=lam&15, a=lam>>4, chunk c=4wv+a (k in [16c,16c+16)),
// rows r=4m..4m+3. Its k-range lies inside its own wave's atom segment
// [64wv, 64wv+64) -> h exchange is wave-private (no barrier before matvec).
//
// Per step: poll own atom (8B agent-scope, LLC) -> h_lds -> 4x b128 h reads
// -> 64 FMA -> partials to pt[64][36] -> ONE barrier -> 8-lane row reduce
// (1x ds_read_b128 + 3 shfl) -> gate exchange (3 shfl) -> activations in
// g==0 lanes -> publishers (tid%32==0) store hs + next atom (tag t+1).
// 2-parity atoms are safe: every block consumes all 512 atoms each step, so
// a tag t+2 overwrite transitively requires global tag-t consumption.
// ---------------------------------------------------------------------------
__global__ __launch_bounds__(512, 1) void lstm_scan(const float* __restrict__ W_hh,
                                                    const float* __restrict__ xg,
                                                    float* __restrict__ hs,
                                                    uint64_t* __restrict__ atoms) {
    __shared__ float h_lds[512];
    __shared__ float pt[64 * 36 + 4];
    const int tid = threadIdx.x;
    const int wv = tid >> 6;
    const int lam = tid & 63;
    const int j = blockIdx.x;                 // 0..31
    const int m = lam & 15;
    const int c = (wv << 2) | (lam >> 4);     // k chunk: [16c, 16c+16)

    // ---- W: 4 rows x 16 k per thread, pinned via asm loads (R3 recipe) ----
    f32x4 w[16];
#pragma unroll
    for (int i = 0; i < 4; ++i) {
        const float* wp = W_hh + (size_t)((i << 9) + (j << 4) + m) * HDIM + (c << 4);
        asm volatile("global_load_dwordx4 %0, %4, off\n\t"
                     "global_load_dwordx4 %1, %4, off offset:16\n\t"
                     "global_load_dwordx4 %2, %4, off offset:32\n\t"
                     "global_load_dwordx4 %3, %4, off offset:48\n\t"
                     "s_waitcnt vmcnt(0)"
                     : "=v"(w[4 * i]), "=v"(w[4 * i + 1]),
                       "=v"(w[4 * i + 2]), "=v"(w[4 * i + 3])
                     : "v"(wp));
    }

    // ---- reduce-role constants ----
    const int rrow = tid >> 3;                // row this thread reduces (0..63)
    const int s8 = tid & 7;
    const int gg = rrow & 3;                  // gate id (0=i,1=f,2=g,3=o)
    const int uu = rrow >> 2;                 // element within block (0..15)
    const size_t xcol = (size_t)(gg << 9) + (j << 4) + uu;
    const bool actv = (gg == 0);
    const bool publ = actv && (s8 == 0);      // tid % 32 == 0

    float cstate = 0.f;
    float xv = __builtin_nontemporal_load(&xg[xcol]);   // step 0

    for (int t = 0; t < T_LEN; ++t) {
        const int par = t & 1;

        // ---- poll own atom (LLC, agent scope — R1-proven) ----
        uint64_t u;
        {
            uint64_t* src = atoms + (par << 9) + tid;
            int guard = 0;
            do {
                u = __hip_atomic_load(src, __ATOMIC_RELAXED,
                                      __HIP_MEMORY_SCOPE_AGENT);
            } while ((uint32_t)(u >> 32) != (uint32_t)t && ++guard < (1 << 22));
        }
        h_lds[tid] = __uint_as_float((uint32_t)u);

        // xg prefetch for t+1 (drained by next step's poll)
        float xv_nx = 0.f;
        if (t + 1 < T_LEN)
            xv_nx = __builtin_nontemporal_load(&xg[(size_t)(t + 1) * G4 + xcol]);

        // ---- matvec partials: 4 rows x 16 k (wave-private h) ----
        const float* hp = &h_lds[c << 4];
        f32x4 h0 = *(const f32x4*)(hp + 0);
        f32x4 h1 = *(const f32x4*)(hp + 4);
        f32x4 h2 = *(const f32x4*)(hp + 8);
        f32x4 h3 = *(const f32x4*)(hp + 12);
        float p0 = 0.f, p1 = 0.f, p2 = 0.f, p3 = 0.f;
#pragma unroll
        for (int e = 0; e < 4; ++e) {
            p0 += w[0][e] * h0[e] + w[1][e] * h1[e] + w[2][e] * h2[e] + w[3][e] * h3[e];
            p1 += w[4][e] * h0[e] + w[5][e] * h1[e] + w[6][e] * h2[e] + w[7][e] * h3[e];
            p2 += w[8][e] * h0[e] + w[9][e] * h1[e] + w[10][e] * h2[e] + w[11][e] * h3[e];
            p3 += w[12][e] * h0[e] + w[13][e] * h1[e] + w[14][e] * h2[e] + w[15][e] * h3[e];
        }
        {
            const int rb = m << 2;            // first row = 4m
            pt[(rb + 0) * 36 + c] = p0;
            pt[(rb + 1) * 36 + c] = p1;
            pt[(rb + 2) * 36 + c] = p2;
            pt[(rb + 3) * 36 + c] = p3;
        }
        __syncthreads();                      // the single barrier per step

        // ---- distributed reduce: 8 lanes per row ----
        f32x4 pv = *(const f32x4*)&pt[rrow * 36 + (s8 << 2)];
        float S = (pv[0] + pv[1]) + (pv[2] + pv[3]);
        S += __shfl_xor(S, 1);
        S += __shfl_xor(S, 2);
        S += __shfl_xor(S, 4);
        S += xv;                              // x-gate + bias (folded)

        // gate exchange within the 32-lane element group
        float Bf = __shfl_xor(S, 8);          // gate g^1
        float Cg = __shfl_xor(S, 16);         // gate g^2
        float Do = __shfl_xor(Cg, 8);         // gate g^3

        if (actv) {                           // lanes with g==0: (S,Bf,Cg,Do)=(i,f,g,o)
            float iv = 1.f / (1.f + __expf(-S));
            float fv = 1.f / (1.f + __expf(-Bf));
            float gv = 2.f / (1.f + __expf(-2.f * Cg)) - 1.f;
            float ov = 1.f / (1.f + __expf(-Do));
            cstate = fv * cstate + iv * gv;
            float hv = ov * (2.f / (1.f + __expf(-2.f * cstate)) - 1.f);
            if (publ) {
                hs[(size_t)t * HDIM + (j << 4) + uu] = hv;
                uint64_t pu = ((uint64_t)(uint32_t)(t + 1) << 32) |
                              (uint64_t)__float_as_uint(hv);
                __hip_atomic_store(atoms + (((t + 1) & 1) << 9) + (j << 4) + uu,
                                   pu, __ATOMIC_RELAXED, __HIP_MEMORY_SCOPE_AGENT);
            }
        }
        xv = xv_nx;
        // pt reuse without a 2nd barrier is safe: any wave's next-step pt
        // write is gated (via its poll) on every block's publishers, which
        // publish only after their own pt reads this step.
    }
}

// ---------------------------------------------------------------------------
__global__ __launch_bounds__(256) void heads_k(const float* __restrict__ inter,
                                               const float* __restrict__ fc1w,
                                               const float* __restrict__ fc1b,
                                               const float* __restrict__ fc2w,
                                               const float* __restrict__ fc2b,
                                               float* __restrict__ out) {
    __shared__ float it[64][128];
    __shared__ float wt[128][56];
    __shared__ float bl[56];
    const int tid = threadIdx.x;
    const int t0 = blockIdx.x << 6;
    for (int q = tid; q < 64 * 32; q += 256) {
        int r = q >> 5, c4 = q & 31;
        *(float4*)&it[r][c4 << 2] =
            *(const float4*)&inter[(size_t)(t0 + r) * 128 + (c4 << 2)];
    }
    for (int q = tid; q < 53 * 32; q += 256) {
        int r = q >> 5, c4 = q & 31;
        float4 v = (r < 16) ? ((const float4*)&fc1w[r * 128])[c4]
                            : ((const float4*)&fc2w[(r - 16) * 128])[c4];
        int k = c4 << 2;
        wt[k + 0][r] = v.x; wt[k + 1][r] = v.y; wt[k + 2][r] = v.z; wt[k + 3][r] = v.w;
    }
    if (tid < 53) bl[tid] = (tid < 16) ? fc1b[tid] : fc2b[tid - 16];
    __syncthreads();
    const int c = tid & 63, rg = tid >> 6;
    if (c < 53) {
        float b = bl[c];
        for (int rr = 0; rr < 16; ++rr) {
            int r = (rg << 4) + rr;
            float acc = b;
#pragma unroll 8
            for (int k = 0; k < 128; k += 4) {
                float4 iv = *(const float4*)&it[r][k];
                acc += iv.x * wt[k][c] + iv.y * wt[k + 1][c] +
                       iv.z * wt[k + 2][c] + iv.w * wt[k + 3][c];
            }
            acc = fminf(fmaxf(acc, 0.f), CLAMP_MAXV);
            int t = t0 + r;
            if (c < 16) out[(size_t)t * 16 + c] = acc;
            else        out[262144 + (size_t)t * 37 + (c - 16)] = acc;
        }
    }
}

// ---------------------------------------------------------------------------
extern "C" void kernel_launch(void* const* d_in, const int* in_sizes, int n_in,
                              void* d_out, int out_size, void* d_ws, size_t ws_size,
                              hipStream_t stream) {
    const float* x     = (const float*)d_in[0];
    const float* W_ih  = (const float*)d_in[1];
    const float* W_hh  = (const float*)d_in[2];
    const float* b_ih  = (const float*)d_in[3];
    const float* b_hh  = (const float*)d_in[4];
    const float* fc_w  = (const float*)d_in[5];
    const float* fc_b  = (const float*)d_in[6];
    const float* fc1_w = (const float*)d_in[7];
    const float* fc1_b = (const float*)d_in[8];
    const float* fc2_w = (const float*)d_in[9];
    const float* fc2_b = (const float*)d_in[10];

    if (ws_size < WS_NEED) return;

    char* ws = (char*)d_ws;
    float*    xg    = (float*)(ws + XG_OFF);
    float*    hs    = (float*)(ws + HS_OFF);
    float*    inter = (float*)(ws + INTER_OFF);
    uint64_t* atoms = (uint64_t*)(ws + ATOM_OFF);
    float*    bsum  = (float*)(ws + BSUM_OFF);
    float*    out   = (float*)d_out;

    hipLaunchKernelGGL(init_k, dim3(8), dim3(256), 0, stream,
                       atoms, b_ih, b_hh, bsum);
    hipLaunchKernelGGL(gemm_abt, dim3(256, 32), dim3(256), 0, stream,
                       x, W_ih, bsum, xg, 2048, 512);
    hipLaunchKernelGGL(lstm_scan, dim3(32), dim3(512), 0, stream,
                       W_hh, xg, hs, atoms);
    hipLaunchKernelGGL(gemm_abt, dim3(256, 2), dim3(256), 0, stream,
                       hs, fc_w, fc_b, inter, 128, 512);
    hipLaunchKernelGGL(heads_k, dim3(256), dim3(256), 0, stream,
                       inter, fc1_w, fc1_b, fc2_w, fc2_b, out);
}